// Round 10
// baseline (180.876 us; speedup 1.0000x reference)
//
#include <hip/hip_runtime.h>
#include <stdint.h>

// ---------------------------------------------------------------------------
// MultiheadMaskedAttention (B=2, S=2048, H=1024, 16 heads x d=64)
// R10: attn is LDS-pipe-bound (R9: ~264 LDS cyc/wave-iter x 67.6k iters =
// ~29 of 43 us). Fix: 32-row waves (halve per-FLOP LDS bytes) + 2-way
// KV(t)-parity split (keep 4096 resident waves) + R6's in-register S^T->PV
// (16x16x16, no P LDS round-trip; V A-frags = b64 reads, 8KB/iter).
// One LDS pair-merge at end (linear O,l). 1024 blocks x 256 thr, 32KB LDS
// (merge buf overlaps dead KV region) -> 4 blocks/CU. GEMMs/prep unchanged.
// ---------------------------------------------------------------------------

typedef __bf16 bf16;
typedef __attribute__((ext_vector_type(8))) __bf16 bf16x8;
typedef __attribute__((ext_vector_type(4))) __bf16 bf16x4;
typedef __attribute__((ext_vector_type(4))) float floatx4;
typedef __attribute__((ext_vector_type(4))) short short4v;

#define SCL 0.18033688011112042f  // (1/sqrt(64)) * log2(e)

__device__ __forceinline__ floatx4 mfma_bf16(bf16x8 a, bf16x8 b, floatx4 c) {
  // A: m=lane&15, k=quad*8+j ; B: n=lane&15, k=quad*8+j ; D: n=lane&15,
  // m=quad*4+reg  [verified m89/m91]
  return __builtin_amdgcn_mfma_f32_16x16x32_bf16(a, b, c, 0, 0, 0);
}
__device__ __forceinline__ floatx4 mfma16(short4v a, short4v b, floatx4 c) {
  // 16x16x16 bf16 (_1k): A: m=lane&15, k=quad*4+j; B: k=quad*4+j, n=lane&15;
  // D: n=lane&15, m=quad*4+reg  [R6-proven correct]
  return __builtin_amdgcn_mfma_f32_16x16x16bf16_1k(a, b, c, 0, 0, 0);
}

__device__ __forceinline__ void cp_g2l_16(const bf16* g, bf16* l) {
  __builtin_amdgcn_global_load_lds(
      (const __attribute__((address_space(1))) void*)g,
      (__attribute__((address_space(3))) void*)l, 16, 0, 0);
}

// ---- merged prep: cast x -> bf16 ; cast+transpose w_qkv, w_o ----
__global__ __launch_bounds__(256) void prep_kernel(
    const float* __restrict__ x, bf16* __restrict__ xb,
    const float* __restrict__ w_qkv, bf16* __restrict__ wqkvt,
    const float* __restrict__ w_o, bf16* __restrict__ wot) {
  const int b = blockIdx.x;
  const int tid = threadIdx.x;
  if (b < 4096) {
    const int i = (b * 256 + tid) * 4;
    floatx4 v = *(const floatx4*)(x + i);
    bf16x4 o;
    o[0] = (bf16)v[0]; o[1] = (bf16)v[1]; o[2] = (bf16)v[2]; o[3] = (bf16)v[3];
    *(bf16x4*)(xb + i) = o;
    return;
  }
  __shared__ float tile[32][33];
  const float* W; bf16* Wt; int K, N, n0, k0;
  if (b < 7168) {
    const int bb = b - 4096;
    W = w_qkv; Wt = wqkvt; K = 1024; N = 3072;
    n0 = (bb % 96) * 32; k0 = (bb / 96) * 32;
  } else {
    const int bb = b - 7168;
    W = w_o; Wt = wot; K = 1024; N = 1024;
    n0 = (bb & 31) * 32; k0 = (bb >> 5) * 32;
  }
  const int tx = tid & 31, ty = tid >> 5;
  for (int i = 0; i < 4; ++i)
    tile[ty + 8 * i][tx] = W[(size_t)(k0 + ty + 8 * i) * N + n0 + tx];
  __syncthreads();
  for (int i = 0; i < 4; ++i)
    Wt[(size_t)(n0 + ty + 8 * i) * K + k0 + tx] = (bf16)tile[tx][ty + 8 * i];
}

// ---- GEMM: C = A(M x K bf16 rm) * Bt(N x K bf16 rm)^T + bias ----
template <int MODE, int MI>
__global__ __launch_bounds__(256, 3) void gemm_bt_kernel(
    const bf16* __restrict__ A, const bf16* __restrict__ Bt,
    const float* __restrict__ bias, float* __restrict__ outF,
    bf16* __restrict__ qb, bf16* __restrict__ kb, bf16* __restrict__ vtb,
    int N, int K) {
  constexpr int BM = MI * 32;
  __shared__ bf16 As[BM * 32];
  __shared__ bf16 Bs[128 * 32];
  const int tid = threadIdx.x;
  const int w = tid >> 6, lane = tid & 63;
  const int l16 = lane & 15, quad = lane >> 4;
  const int m0 = blockIdx.y * BM, n0 = blockIdx.x * 128;
  const int wm = (w & 1) * (BM / 2), wn = (w >> 1) * 64;

  const int arow = w * (BM / 4) + (lane >> 2);
  const int acol = (lane & 3) * 8;
  const bf16* Ag = A + (size_t)(m0 + arow) * K + acol;
  bf16* Al = As + arow * 32 + acol;
  const int brow = w * 32 + (lane >> 2);
  const bf16* Bg = Bt + (size_t)(n0 + brow) * K + acol;
  bf16* Bl = Bs + brow * 32 + acol;

  floatx4 acc[MI][4];
#pragma unroll
  for (int i = 0; i < MI; ++i)
#pragma unroll
    for (int j = 0; j < 4; ++j) acc[i][j] = (floatx4){0.f, 0.f, 0.f, 0.f};

  for (int k0 = 0; k0 < K; k0 += 32) {
    __syncthreads();
    cp_g2l_16(Ag + k0, Al);
    if (MI == 4) cp_g2l_16(Ag + (size_t)16 * K + k0, Al + 16 * 32);
    cp_g2l_16(Bg + k0, Bl);
    cp_g2l_16(Bg + (size_t)16 * K + k0, Bl + 16 * 32);
    __syncthreads();
    bf16x8 af[MI], bfr[4];
#pragma unroll
    for (int i = 0; i < MI; ++i)
      af[i] = *(const bf16x8*)(&As[(wm + i * 16 + l16) * 32 + quad * 8]);
#pragma unroll
    for (int j = 0; j < 4; ++j)
      bfr[j] = *(const bf16x8*)(&Bs[(wn + j * 16 + l16) * 32 + quad * 8]);
#pragma unroll
    for (int i = 0; i < MI; ++i)
#pragma unroll
      for (int j = 0; j < 4; ++j)
        acc[i][j] = mfma_bf16(af[i], bfr[j], acc[i][j]);
  }

#pragma unroll
  for (int i = 0; i < MI; ++i)
#pragma unroll
    for (int j = 0; j < 4; ++j) {
      const int nn = n0 + wn + j * 16 + l16;
      const float bv = bias[nn];
      const int mbase = m0 + wm + i * 16 + quad * 4;
      if (MODE == 1) {
#pragma unroll
        for (int r = 0; r < 4; ++r)
          outF[(size_t)(mbase + r) * N + nn] = acc[i][j][r] + bv;
      } else {
        const int which = nn >> 10;  // uniform per block
        const int rem = nn & 1023;
        const int h = rem >> 6, d = rem & 63;
        const int b = mbase >> 11, s = mbase & 2047;
        const size_t bh = (size_t)(b * 16 + h);
        if (which == 2) {
          bf16x4 pk;
#pragma unroll
          for (int r = 0; r < 4; ++r) pk[r] = (bf16)(acc[i][j][r] + bv);
          *(bf16x4*)(vtb + (bh * 64 + d) * 2048 + s) = pk;
        } else if (which == 0) {
#pragma unroll
          for (int r = 0; r < 4; ++r)
            qb[(bh * 2048 + s + r) * 64 + d] = (bf16)((acc[i][j][r] + bv) * SCL);
        } else {
#pragma unroll
          for (int r = 0; r < 4; ++r)
            kb[(bh * 2048 + s + r) * 64 + d] = (bf16)(acc[i][j][r] + bv);
        }
      }
    }
}

// ---- Flash attention, causal: 32-row waves, parity KV split, reg-PV. ----
// 1024 blocks x 256 thr. Block = (head, pair {j, 63-j}); waves 0,1 = 32-row
// tile j with t-parity 0,1; waves 2,3 = tile 63-j. Each (tile,t) processed
// by exactly one wave -> LDS reads = 540 MB total (half of R9). S^T = K*Q^T
// (A=kf from staged Ks); P^T = exp2 in-register (C-frag == 16x16x16 B-frag);
// PV: O^T[d][q] += V^T(A, b64 from staged Vs) x P^T(B). l via ones-A MFMA.
// Pair-merge (sum O,l) through LDS overlapping the dead KV region.
__global__ __launch_bounds__(256, 4) void attn_kernel(
    const bf16* __restrict__ Qb, const bf16* __restrict__ Kb,
    const bf16* __restrict__ Vtb, bf16* __restrict__ attnb) {
  __shared__ __align__(16) char smem[32768];  // KV dbuf; merge buf after loop
  bf16* Ks0 = (bf16*)smem;            // [2][4096]
  bf16* Vs0 = (bf16*)(smem + 16384);  // [2][4096]
  const int bid = blockIdx.x;
  const int bh = (bid & 7) * 4 + ((bid >> 3) & 3);  // 4 heads per XCD
  const int j = bid >> 5;                           // pair id 0..31, big first
  const int tid = threadIdx.x;
  const int w = tid >> 6, lane = tid & 63;
  const int l16 = lane & 15, quad = lane >> 4;
  const int tile = (w < 2) ? j : (63 - j);  // this wave's 32-row q-tile
  const int par = w & 1;                    // t-parity this wave owns
  const int q0 = tile * 32;
  const int D = tile >> 1;                  // diagonal 64-col KV tile
  const int b = bh >> 4, h = bh & 15;
  const bf16* Qh = Qb + (size_t)bh * 2048 * 64;
  const bf16* Kh = Kb + (size_t)bh * 2048 * 64;
  const bf16* Vh = Vtb + (size_t)bh * 64 * 2048;

  const int nt = ((63 - j) >> 1) + 1;  // block staging iterations (max range)

  // staging: thread copies chunks {tid, tid+256} of K and V (512 each)
  // dest chunk c: row=c>>3, slot=c&7 holds source chunk (slot-row)&7
  const int c0 = tid, c1 = 256 + tid;
  const int ksrc0 = (c0 >> 3) * 64 + (((c0 & 7) - (c0 >> 3)) & 7) * 8;
  const int ksrc1 = (c1 >> 3) * 64 + (((c1 & 7) - (c1 >> 3)) & 7) * 8;
  const int vsrc0 = (c0 >> 3) * 2048 + (((c0 & 7) - (c0 >> 3)) & 7) * 8;
  const int vsrc1 = (c1 >> 3) * 2048 + (((c1 & 7) - (c1 >> 3)) & 7) * 8;

  // Q B-frags (n=q=l16, k=d) for both 16-row halves, resident all kernel
  bf16x8 qf[2][2];
#pragma unroll
  for (int mb = 0; mb < 2; ++mb)
#pragma unroll
    for (int kq = 0; kq < 2; ++kq)
      qf[mb][kq] = *(const bf16x8*)(Qh + (size_t)(q0 + mb * 16 + l16) * 64 +
                                    kq * 32 + quad * 8);
  short4v onesA;
#pragma unroll
  for (int i = 0; i < 4; ++i) onesA[i] = (short)0x3F80;  // bf16 1.0

  // O^T accumulators: [md][mb] C-frags, lane holds q=mb*16+l16,
  // d=md*16+quad*4+r ; Ol = l (all 4 regs equal)
  floatx4 O[4][2], Ol[2];
#pragma unroll
  for (int md = 0; md < 4; ++md)
#pragma unroll
    for (int mb = 0; mb < 2; ++mb) O[md][mb] = (floatx4){0.f, 0.f, 0.f, 0.f};
  Ol[0] = (floatx4){0.f, 0.f, 0.f, 0.f};
  Ol[1] = (floatx4){0.f, 0.f, 0.f, 0.f};

  // prologue: stage tile 0 into buffer 0
  cp_g2l_16(Kh + ksrc0, Ks0 + c0 * 8);
  cp_g2l_16(Kh + ksrc1, Ks0 + c1 * 8);
  cp_g2l_16(Vh + vsrc0, Vs0 + c0 * 8);
  cp_g2l_16(Vh + vsrc1, Vs0 + c1 * 8);

  int cur = 0;
  for (int t = 0; t < nt; ++t, cur ^= 1) {
    __syncthreads();  // buf[cur] staged; all waves done with buf[cur^1]
    if (t + 1 < nt) {
      const int nb = cur ^ 1;
      cp_g2l_16(Kh + (size_t)(t + 1) * 4096 + ksrc0, Ks0 + nb * 4096 + c0 * 8);
      cp_g2l_16(Kh + (size_t)(t + 1) * 4096 + ksrc1, Ks0 + nb * 4096 + c1 * 8);
      cp_g2l_16(Vh + (t + 1) * 64 + vsrc0, Vs0 + nb * 4096 + c0 * 8);
      cp_g2l_16(Vh + (t + 1) * 64 + vsrc1, Vs0 + nb * 4096 + c1 * 8);
    }

    if (t > D || (t & 1) != par) continue;  // not this wave's tile
    const bool diag = (t == D);
    const bf16* KsC = Ks0 + cur * 4096;
    const bf16* VsC = Vs0 + cur * 4096;

    // S^T = K * Q^T, both 16-row q-halves; kq-loop keeps kf at 16 regs
    floatx4 sf[2][4];
#pragma unroll
    for (int mb = 0; mb < 2; ++mb)
#pragma unroll
      for (int nk = 0; nk < 4; ++nk) sf[mb][nk] = (floatx4){0.f, 0.f, 0.f, 0.f};
#pragma unroll
    for (int kq = 0; kq < 2; ++kq) {
      bf16x8 kf[4];
#pragma unroll
      for (int nk = 0; nk < 4; ++nk) {
        const int row = nk * 16 + l16;
        kf[nk] = *(const bf16x8*)(
            &KsC[row * 64 + ((kq * 4 + quad + row) & 7) * 8]);
      }
#pragma unroll
      for (int mb = 0; mb < 2; ++mb)
#pragma unroll
        for (int nk = 0; nk < 4; ++nk)
          sf[mb][nk] = mfma_bf16(kf[nk], qf[mb][kq], sf[mb][nk]);
    }

    // mask -> exp2 -> pack P^T B-frags in-register (no LDS)
    short4v Pt[2][4];
#pragma unroll
    for (int mb = 0; mb < 2; ++mb)
#pragma unroll
      for (int nk = 0; nk < 4; ++nk) {
#pragma unroll
        for (int r = 0; r < 4; ++r) {
          float s = sf[mb][nk][r];
          if (diag) {
            const int kc = t * 64 + nk * 16 + quad * 4 + r;
            const int qrow = q0 + mb * 16 + l16;
            s = (kc <= qrow) ? s : -1e30f;
          }
          Pt[mb][nk][r] =
              __builtin_bit_cast(short, (bf16)__builtin_amdgcn_exp2f(s));
        }
        Ol[mb] = mfma16(onesA, Pt[mb][nk], Ol[mb]);
      }

    // O^T += V^T x P^T ; vf loaded once per (md,nk), used for both mb
#pragma unroll
    for (int md = 0; md < 4; ++md) {
      const int row = md * 16 + l16;
#pragma unroll
      for (int nk = 0; nk < 4; ++nk) {
        const int c = nk * 2 + (quad >> 1);
        const int off = (quad & 1) * 4;
        short4v vfr = *(const short4v*)(
            &VsC[row * 64 + ((c + row) & 7) * 8 + off]);
        O[md][0] = mfma16(vfr, Pt[0][nk], O[md][0]);
        O[md][1] = mfma16(vfr, Pt[1][nk], O[md][1]);
      }
    }
  }

  // ---- pair-merge (odd wave -> LDS, even wave adds) and epilogue ----
  __syncthreads();  // KV region dead; reuse as merge buffer
  float* Cb = (float*)smem + (w >> 1) * 2304;  // per-pair 9216 B
  if (par) {
#pragma unroll
    for (int md = 0; md < 4; ++md)
#pragma unroll
      for (int mb = 0; mb < 2; ++mb)
        *(floatx4*)(Cb + ((md * 2 + mb) * 64 + lane) * 4) = O[md][mb];
    Cb[2048 + 0 * 64 + lane] = Ol[0][0];
    Cb[2048 + 1 * 64 + lane] = Ol[1][0];
  }
  __syncthreads();
  if (!par) {
#pragma unroll
    for (int md = 0; md < 4; ++md)
#pragma unroll
      for (int mb = 0; mb < 2; ++mb)
        O[md][mb] += *(const floatx4*)(Cb + ((md * 2 + mb) * 64 + lane) * 4);
    const float l0 = Ol[0][0] + Cb[2048 + 0 * 64 + lane];
    const float l1 = Ol[1][0] + Cb[2048 + 1 * 64 + lane];
    // epilogue: lane q=q0+mb*16+l16 fixed, d=md*16+quad*4+r -> b64 stores
#pragma unroll
    for (int mb = 0; mb < 2; ++mb) {
      const float inv = 1.f / (mb ? l1 : l0);
      const size_t rowbase = ((size_t)(b * 2048 + q0 + mb * 16 + l16)) * 1024;
#pragma unroll
      for (int md = 0; md < 4; ++md) {
        bf16x4 pk;
#pragma unroll
        for (int r = 0; r < 4; ++r) pk[r] = (bf16)(O[md][mb][r] * inv);
        *(bf16x4*)(attnb + rowbase + h * 64 + md * 16 + quad * 4) = pk;
      }
    }
  }
}

// ---------------------------------------------------------------------------
extern "C" void kernel_launch(void* const* d_in, const int* in_sizes, int n_in,
                              void* d_out, int out_size, void* d_ws, size_t ws_size,
                              hipStream_t stream) {
  const float* x     = (const float*)d_in[0];  // (2,2048,1024)
  const float* w_qkv = (const float*)d_in[1];  // (1024,3072)
  const float* b_qkv = (const float*)d_in[2];  // (3072)
  const float* w_o   = (const float*)d_in[3];  // (1024,1024)
  const float* b_o   = (const float*)d_in[4];  // (1024)
  float* out = (float*)d_out;                  // (2,2048,1024) fp32

  char* ws = (char*)d_ws;
  bf16* xb    = (bf16*)ws; ws += (size_t)4096 * 1024 * 2;
  bf16* wqkvt = (bf16*)ws; ws += (size_t)3072 * 1024 * 2;
  bf16* wot   = (bf16*)ws; ws += (size_t)1024 * 1024 * 2;
  bf16* qb    = (bf16*)ws; ws += (size_t)32 * 2048 * 64 * 2;
  bf16* kb    = (bf16*)ws; ws += (size_t)32 * 2048 * 64 * 2;
  bf16* vtb   = (bf16*)ws; ws += (size_t)32 * 2048 * 64 * 2;  // (bh,64,S)
  bf16* attnb = (bf16*)ws; ws += (size_t)4096 * 1024 * 2;

  prep_kernel<<<8192, 256, 0, stream>>>(x, xb, w_qkv, wqkvt, w_o, wot);
  gemm_bt_kernel<0, 4><<<dim3(24, 32), 256, 0, stream>>>(
      xb, wqkvt, b_qkv, nullptr, qb, kb, vtb, 3072, 1024);
  attn_kernel<<<1024, 256, 0, stream>>>(qb, kb, vtb, attnb);
  gemm_bt_kernel<1, 2><<<dim3(8, 64), 256, 0, stream>>>(
      attnb, wot, b_o, out, nullptr, nullptr, nullptr, 1024, 1024);
}